// Round 6
// baseline (1652.574 us; speedup 1.0000x reference)
//
#include <hip/hip_runtime.h>

// ---------------------------------------------------------------------------
// Encoder_Decoder: 80-class bidirectional GRU encoder (H=128) + GRU decoder
// (DH=256) with teacher forcing, plus two shared dense layers.
// v6: weight storage rewritten from local ARRAYS to NAMED ext-vector
// variables. v2-v5 all showed VGPR_Count=84 + 27MB scratch regardless of
// occupancy attributes: SROA runs before unroll, so the runtime-indexed
// weight arrays survived as allocas and AMDGPUPromoteAlloca rejected the
// 512B aggregates -> assigned to scratch at IR level (guide rule #20).
// Named h8 variables (built via macros, sliced with constant-index
// shufflevector) are SSA from the start and MUST live in VGPRs.
// ---------------------------------------------------------------------------

typedef __fp16 h2v __attribute__((ext_vector_type(2)));
typedef __fp16 h8 __attribute__((ext_vector_type(8)));

__device__ __forceinline__ h2v pk2(float a, float b) {
  return __builtin_amdgcn_cvt_pkrtz(a, b);
}
__device__ __forceinline__ unsigned h2u(h2v h) { return __builtin_bit_cast(unsigned, h); }
__device__ __forceinline__ h2v u2h(unsigned u) { return __builtin_bit_cast(h2v, u); }
__device__ __forceinline__ float fdot2f(h2v a, h2v b, float c) {
  return __builtin_amdgcn_fdot2(a, b, c, false);
}
__device__ __forceinline__ float sigf(float x) { return 1.f / (1.f + __expf(-x)); }
__device__ __forceinline__ float tanhfast(float x) { return 2.f / (1.f + __expf(-2.f * x)) - 1.f; }

__device__ __forceinline__ h8 pack8(float4 a, float4 b) {
  h2v p0 = pk2(a.x, a.y), p1 = pk2(a.z, a.w), p2 = pk2(b.x, b.y), p3 = pk2(b.z, b.w);
  return (h8){p0[0], p0[1], p1[0], p1[1], p2[0], p2[1], p3[0], p3[1]};
}

// constant-index h2v slice of an h8 (subregister alias, no code)
#define SL(V, j) (__builtin_shufflevector((V), (V), 2 * (j), 2 * (j) + 1))

// acc + (partner-lane v) via DPP. CTRL: 0xB1 = quad_perm[1,0,3,2] (xor1),
// 0x4E = quad_perm[2,3,0,1] (xor2), 0x128 = row_ror:8 (xor8 within 16-row).
template <int CTRL>
__device__ __forceinline__ float dppadd(float acc, float v) {
  int r = __builtin_amdgcn_update_dpp(0, __float_as_int(v), CTRL, 0xF, 0xF, true);
  return acc + __int_as_float(r);
}
// xor-4 via ds_swizzle BitMode: (4<<10)|0x1F
__device__ __forceinline__ float swz4add(float acc, float v) {
  return acc + __int_as_float(__builtin_amdgcn_ds_swizzle(__float_as_int(v), 0x101F));
}

// Reduce 8 partials (arg k on lane holds row-id k^(m&7)) across a 16-lane
// group; returns the full sum for row-id (m&7) (identical on lanes m, m^8).
__device__ __forceinline__ float reduce8s(float p0, float p1, float p2, float p3,
                                          float p4, float p5, float p6, float p7) {
  p0 = dppadd<0xB1>(p0, p1);
  p2 = dppadd<0xB1>(p2, p3);
  p4 = dppadd<0xB1>(p4, p5);
  p6 = dppadd<0xB1>(p6, p7);
  p0 = dppadd<0x4E>(p0, p2);
  p4 = dppadd<0x4E>(p4, p6);
  p0 = swz4add(p0, p4);
  p0 = dppadd<0x128>(p0, p0);
  return p0;
}

// 8-col dot: h8 weight slice vs 4 h2v activations
__device__ __forceinline__ float dot4(h8 V, h2v a0, h2v a1, h2v a2, h2v a3, float acc) {
  acc = fdot2f(SL(V, 0), a0, acc);
  acc = fdot2f(SL(V, 1), a1, acc);
  acc = fdot2f(SL(V, 2), a2, acc);
  acc = fdot2f(SL(V, 3), a3, acc);
  return acc;
}

// ---------------------------------------------------------------------------
// K0: fill allf[:,128:224] with score|box|origin_score
// ---------------------------------------------------------------------------
__global__ void k_fill_misc(const float* __restrict__ score, const float* __restrict__ box,
                            const float* __restrict__ orig, float* __restrict__ allf) {
  int i = blockIdx.x * blockDim.x + threadIdx.x;
  if (i >= 40960 * 96) return;
  int row = i / 96, k = i - row * 96;
  float v;
  if (k == 0) v = score[row];
  else if (k < 5) v = box[row * 4 + (k - 1)];
  else v = orig[(size_t)row * 91 + (k - 5)];
  allf[(size_t)row * 224 + 128 + k] = v;
}

// ---------------------------------------------------------------------------
// K1: allf[:,0:128] = relu(feat @ appear_W^T + appear_b)
// ---------------------------------------------------------------------------
__global__ __launch_bounds__(256) void k_gemm_appear(
    const float* __restrict__ A, const float* __restrict__ W,
    const float* __restrict__ bias, float* __restrict__ allf) {
  __shared__ float As[32][68];
  __shared__ float Ws[32][132];
  const int tid = threadIdx.x;
  const int tx = tid & 15, ty = tid >> 4;
  const int r0 = blockIdx.x * 64;
  const int lr = tid >> 3;
  const int lk = (tid & 7) * 4;
  float acc[4][8];
#pragma unroll
  for (int i = 0; i < 4; ++i)
#pragma unroll
    for (int j = 0; j < 8; ++j) acc[i][j] = 0.f;

  for (int k0 = 0; k0 < 1024; k0 += 32) {
#pragma unroll
    for (int i = 0; i < 2; ++i) {
      int rr = lr + i * 32;
      float4 v = *(const float4*)(A + (size_t)(r0 + rr) * 1024 + k0 + lk);
      As[lk + 0][rr] = v.x; As[lk + 1][rr] = v.y; As[lk + 2][rr] = v.z; As[lk + 3][rr] = v.w;
    }
#pragma unroll
    for (int i = 0; i < 4; ++i) {
      int wr = lr + i * 32;
      float4 v = *(const float4*)(W + (size_t)wr * 1024 + k0 + lk);
      Ws[lk + 0][wr] = v.x; Ws[lk + 1][wr] = v.y; Ws[lk + 2][wr] = v.z; Ws[lk + 3][wr] = v.w;
    }
    __syncthreads();
#pragma unroll
    for (int kk = 0; kk < 32; ++kk) {
      float4 a = *(const float4*)&As[kk][ty * 4];
      float4 w0 = *(const float4*)&Ws[kk][tx * 8];
      float4 w1 = *(const float4*)&Ws[kk][tx * 8 + 4];
      float av[4] = {a.x, a.y, a.z, a.w};
      float wv[8] = {w0.x, w0.y, w0.z, w0.w, w1.x, w1.y, w1.z, w1.w};
#pragma unroll
      for (int i = 0; i < 4; ++i)
#pragma unroll
        for (int j = 0; j < 8; ++j) acc[i][j] = fmaf(av[i], wv[j], acc[i][j]);
    }
    __syncthreads();
  }
#pragma unroll
  for (int i = 0; i < 4; ++i) {
    int row = r0 + ty * 4 + i;
#pragma unroll
    for (int j = 0; j < 8; ++j) {
      int col = tx * 8 + j;
      float v = acc[i][j] + bias[col];
      allf[(size_t)row * 224 + col] = fmaxf(v, 0.f);
    }
  }
}

// ---------------------------------------------------------------------------
// K2: enc_feat = relu(allf @ featlin_W^T + b), stored packed f16x2
// ---------------------------------------------------------------------------
__global__ __launch_bounds__(256) void k_gemm_featlin(
    const float* __restrict__ A, const float* __restrict__ W,
    const float* __restrict__ bias, unsigned* __restrict__ encf2) {
  __shared__ float As[32][68];
  __shared__ float Ws[32][132];
  const int tid = threadIdx.x;
  const int tx = tid & 15, ty = tid >> 4;
  const int r0 = blockIdx.x * 64;
  const int lr = tid >> 3;
  const int lk = (tid & 7) * 4;
  float acc[4][8];
#pragma unroll
  for (int i = 0; i < 4; ++i)
#pragma unroll
    for (int j = 0; j < 8; ++j) acc[i][j] = 0.f;

  for (int k0 = 0; k0 < 224; k0 += 32) {
#pragma unroll
    for (int i = 0; i < 2; ++i) {
      int rr = lr + i * 32;
      float4 v = *(const float4*)(A + (size_t)(r0 + rr) * 224 + k0 + lk);
      As[lk + 0][rr] = v.x; As[lk + 1][rr] = v.y; As[lk + 2][rr] = v.z; As[lk + 3][rr] = v.w;
    }
#pragma unroll
    for (int i = 0; i < 4; ++i) {
      int wr = lr + i * 32;
      float4 v = *(const float4*)(W + (size_t)wr * 224 + k0 + lk);
      Ws[lk + 0][wr] = v.x; Ws[lk + 1][wr] = v.y; Ws[lk + 2][wr] = v.z; Ws[lk + 3][wr] = v.w;
    }
    __syncthreads();
#pragma unroll
    for (int kk = 0; kk < 32; ++kk) {
      float4 a = *(const float4*)&As[kk][ty * 4];
      float4 w0 = *(const float4*)&Ws[kk][tx * 8];
      float4 w1 = *(const float4*)&Ws[kk][tx * 8 + 4];
      float av[4] = {a.x, a.y, a.z, a.w};
      float wv[8] = {w0.x, w0.y, w0.z, w0.w, w1.x, w1.y, w1.z, w1.w};
#pragma unroll
      for (int i = 0; i < 4; ++i)
#pragma unroll
        for (int j = 0; j < 8; ++j) acc[i][j] = fmaf(av[i], wv[j], acc[i][j]);
    }
    __syncthreads();
  }
#pragma unroll
  for (int i = 0; i < 4; ++i) {
    int row = r0 + ty * 4 + i;
    unsigned* orow = encf2 + (size_t)row * 64;
#pragma unroll
    for (int p = 0; p < 4; ++p) {
      int col = tx * 8 + 2 * p;
      float a = fmaxf(acc[i][2 * p] + bias[col], 0.f);
      float b = fmaxf(acc[i][2 * p + 1] + bias[col + 1], 0.f);
      orow[tx * 4 + p] = h2u(pk2(a, b));
    }
  }
}

// ---------------------------------------------------------------------------
// K3: decoder input projections: gi[c][v][r] = dec_Wih[c][r]@dec_emb[v] + bih
// ---------------------------------------------------------------------------
__global__ __launch_bounds__(256) void k_dec_gi(
    const float* __restrict__ Wih, const float* __restrict__ bih,
    const float* __restrict__ emb, float* __restrict__ gi) {
  __shared__ float e[4][32];
  const int c = blockIdx.x, tid = threadIdx.x;
  if (tid < 128) e[tid >> 5][tid & 31] = emb[tid];
  __syncthreads();
#pragma unroll
  for (int i = 0; i < 3; ++i) {
    int r = tid + i * 256;
    const float* w = Wih + ((size_t)c * 768 + r) * 32;
    float b = bih[(size_t)c * 768 + r];
    float a0 = b, a1 = b, a2 = b, a3 = b;
#pragma unroll
    for (int k = 0; k < 32; ++k) {
      float wv = w[k];
      a0 = fmaf(wv, e[0][k], a0);
      a1 = fmaf(wv, e[1][k], a1);
      a2 = fmaf(wv, e[2][k], a2);
      a3 = fmaf(wv, e[3][k], a3);
    }
    gi[((size_t)c * 4 + 0) * 768 + r] = a0;
    gi[((size_t)c * 4 + 1) * 768 + r] = a1;
    gi[((size_t)c * 4 + 2) * 768 + r] = a2;
    gi[((size_t)c * 4 + 3) * 768 + r] = a3;
  }
}

// ---------------------------------------------------------------------------
// K4: per-(class,dir) encoder GRU, 513 steps. 160 blocks x 512 threads.
// 8 waves; each wave: 32 combined r/z rows (Wih·x + Whh·h fused) + 32 single
// rows (i_n for w<4, h_n for w>=4). 16-lane group owns 16 rows x 8 cols.
// Weights: 24 NAMED h8 variables (96 VGPRs) -> guaranteed SSA/registers.
// ---------------------------------------------------------------------------
#define ENCROW(k)                                                                   \
  h8 ci_##k, ch_##k, sg_##k;                                                        \
  {                                                                                 \
    int vc = 32 * w + 8 * q + ((k) ^ mw);                                           \
    const float4* pi = (const float4*)(Wih + (size_t)vc * 128 + 8 * m);             \
    ci_##k = pack8(pi[0], pi[1]);                                                   \
    __builtin_amdgcn_sched_barrier(0);                                              \
    const float4* ph = (const float4*)(Whh + (size_t)vc * 128 + 8 * m);             \
    ch_##k = pack8(ph[0], ph[1]);                                                   \
    __builtin_amdgcn_sched_barrier(0);                                              \
    int s = (w < 4) ? vc : (vc - 128);                                              \
    const float* sb =                                                               \
        (w < 4) ? (Wih + (size_t)(256 + s) * 128) : (Whh + (size_t)(256 + s) * 128);\
    const float4* ps = (const float4*)(sb + 8 * m);                                 \
    sg_##k = pack8(ps[0], ps[1]);                                                   \
    __builtin_amdgcn_sched_barrier(0);                                              \
  }

#define EDOTC(k) dot4(ci_##k, x0, x1, x2, x3, dot4(ch_##k, g0, g1, g2, g3, 0.f))
#define EDOTS(k) dot4(sg_##k, s0, s1, s2, s3, 0.f)

__global__ __launch_bounds__(512)
__attribute__((amdgpu_waves_per_eu(2, 2))) void k_enc_gru(
    const unsigned* __restrict__ encf2,
    const float* __restrict__ WihF, const float* __restrict__ WhhF,
    const float* __restrict__ bihF, const float* __restrict__ bhhF,
    const float* __restrict__ WihB, const float* __restrict__ WhhB,
    const float* __restrict__ bihB, const float* __restrict__ bhhB,
    float* __restrict__ dec_h0) {
  const int blk = blockIdx.x;
  const int c = blk >> 1, dir = blk & 1;
  const int tid = threadIdx.x;
  const int w = tid >> 6, l = tid & 63, q = l >> 4, m = l & 15, mw = m & 7;

  const float* Wih = (dir ? WihB : WihF) + (size_t)c * 384 * 128;
  const float* Whh = (dir ? WhhB : WhhF) + (size_t)c * 384 * 128;
  const float* bih = (dir ? bihB : bihF) + (size_t)c * 384;
  const float* bhh = (dir ? bhhB : bhhF) + (size_t)c * 384;

  __shared__ __align__(16) unsigned x2s[2][64];
  __shared__ __align__(16) unsigned h2s[64];
  __shared__ float aBuf[512];

  ENCROW(0) ENCROW(1) ENCROW(2) ENCROW(3)
  ENCROW(4) ENCROW(5) ENCROW(6) ENCROW(7)

  float bown;
  int ownIdx;
  if (m < 8) {
    int vo = 32 * w + 8 * q + m;
    bown = bih[vo] + bhh[vo];
    ownIdx = vo;
  } else {
    int so = (w < 4) ? (32 * w + 8 * q + mw) : (32 * (w - 4) + 8 * q + mw);
    bown = (w < 4) ? bih[256 + so] : bhh[256 + so];
    ownIdx = (w < 4) ? (256 + so) : (384 + so);
  }

  if (tid < 64) h2s[tid] = 0u;
  if (tid >= 448) {
    int lane = tid - 448;
    x2s[0][lane] = (dir == 0) ? encf2[((size_t)c * 512 + 0) * 64 + lane] : 0x3C003C00u;
  }
  float hreg = 0.f;
  __syncthreads();

  for (int t = 0; t <= 512; ++t) {
    unsigned xpre = 0;
    if (tid >= 448 && t < 512) {  // issue next-x load early; hides under matvec
      int tn = t + 1, lane = tid - 448;
      int row = (dir == 0) ? ((tn < 512) ? tn : -1) : (512 - tn);
      xpre = (row < 0) ? 0x3C003C00u : encf2[((size_t)c * 512 + row) * 64 + lane];
    }
    uint4 xv = ((const uint4*)&x2s[t & 1][0])[m];
    uint4 hv = ((const uint4*)&h2s[0])[m];
    h2v x0 = u2h(xv.x), x1 = u2h(xv.y), x2 = u2h(xv.z), x3 = u2h(xv.w);
    h2v g0 = u2h(hv.x), g1 = u2h(hv.y), g2 = u2h(hv.z), g3 = u2h(hv.w);
    float pA = reduce8s(EDOTC(0), EDOTC(1), EDOTC(2), EDOTC(3),
                        EDOTC(4), EDOTC(5), EDOTC(6), EDOTC(7));
    h2v s0 = (w < 4) ? x0 : g0, s1 = (w < 4) ? x1 : g1;
    h2v s2 = (w < 4) ? x2 : g2, s3 = (w < 4) ? x3 : g3;
    float pB = reduce8s(EDOTS(0), EDOTS(1), EDOTS(2), EDOTS(3),
                        EDOTS(4), EDOTS(5), EDOTS(6), EDOTS(7));
    aBuf[ownIdx] = ((m < 8) ? pA : pB) + bown;
    __syncthreads();
    if (tid < 128) {
      float r = sigf(aBuf[tid]);
      float z = sigf(aBuf[128 + tid]);
      float nn = tanhfast(aBuf[256 + tid] + r * aBuf[384 + tid]);
      float hn = (1.f - z) * nn + z * hreg;
      hreg = hn;
      float other = __shfl_xor(hn, 1, 64);
      if ((tid & 1) == 0) h2s[tid >> 1] = h2u(pk2(hn, other));
    } else if (tid >= 448 && t < 512) {
      x2s[(t + 1) & 1][tid - 448] = xpre;
    }
    __syncthreads();
  }
  if (tid < 128) dec_h0[(size_t)c * 256 + dir * 128 + tid] = hreg;
}

// ---------------------------------------------------------------------------
// K5: per-class decoder GRU + fused out-projection + log_softmax.
// 80 blocks x 768 threads (12 waves = 3 waves/SIMD); wave owns 64 rows;
// 16-lane group owns 16 rows x 16 cols. Weights: 32 NAMED h8 variables
// (128 VGPRs) -> guaranteed registers; waves_per_eu(3,3) budget ~170.
// ---------------------------------------------------------------------------
#define DECROW(kc, k)                                                               \
  h8 wA##kc##_##k, wB##kc##_##k;                                                    \
  {                                                                                 \
    int row = 64 * w + 16 * q + 8 * (kc) + ((k) ^ mw);                              \
    const float4* src = (const float4*)(Whh + ((size_t)c * 768 + row) * 256 + 16 * m);\
    float4 v0 = src[0], v1 = src[1];                                                \
    wA##kc##_##k = pack8(v0, v1);                                                   \
    __builtin_amdgcn_sched_barrier(0);                                              \
    float4 v2 = src[2], v3 = src[3];                                                \
    wB##kc##_##k = pack8(v2, v3);                                                   \
    __builtin_amdgcn_sched_barrier(0);                                              \
  }

#define DDOT(kc, k)                                                        \
  (fdot2f(SL(wB##kc##_##k, 3), g7,                                         \
   fdot2f(SL(wB##kc##_##k, 2), g6,                                         \
   fdot2f(SL(wB##kc##_##k, 1), g5,                                         \
   fdot2f(SL(wB##kc##_##k, 0), g4,                                         \
   fdot2f(SL(wA##kc##_##k, 3), g3,                                         \
   fdot2f(SL(wA##kc##_##k, 2), g2,                                         \
   fdot2f(SL(wA##kc##_##k, 1), g1,                                         \
   fdot2f(SL(wA##kc##_##k, 0), g0, 0.f)))))))))

__global__ __launch_bounds__(768)
__attribute__((amdgpu_waves_per_eu(3, 3))) void k_dec_gru(
    const float* __restrict__ Whh, const float* __restrict__ bhh,
    const float* __restrict__ gi, const float* __restrict__ h0,
    const int* __restrict__ labels,
    const float* __restrict__ outW, const float* __restrict__ outB,
    float* __restrict__ out) {
  const int c = blockIdx.x, tid = threadIdx.x;
  const int w = tid >> 6, l = tid & 63, q = l >> 4, m = l & 15, mw = m & 7;

  __shared__ __align__(16) unsigned h2s[128];
  __shared__ float aBuf[768];
  __shared__ float gisf[2304];
  __shared__ float owsh[1024];
  __shared__ int labs[513];
  __shared__ float red[4][4];

  DECROW(0, 0) DECROW(0, 1) DECROW(0, 2) DECROW(0, 3)
  DECROW(0, 4) DECROW(0, 5) DECROW(0, 6) DECROW(0, 7)
  DECROW(1, 0) DECROW(1, 1) DECROW(1, 2) DECROW(1, 3)
  DECROW(1, 4) DECROW(1, 5) DECROW(1, 6) DECROW(1, 7)

  float bown = bhh[(size_t)c * 768 + 64 * w + l];

  for (int i = tid; i < 2304; i += 768) gisf[i] = gi[(size_t)c * 4 * 768 + i];
  for (int i = tid; i < 1024; i += 768) owsh[i] = outW[i];
  if (tid < 512) labs[tid + 1] = labels[(size_t)c * 512 + tid];
  if (tid == 512) labs[0] = 2;  // SOS
  float b0 = outB[0], b1 = outB[1], b2 = outB[2], b3 = outB[3];
  float hreg = 0.f;
  if (tid < 256) {
    hreg = h0[(size_t)c * 256 + tid];
    float other = __shfl_xor(hreg, 1, 64);
    if ((tid & 1) == 0) h2s[tid >> 1] = h2u(pk2(hreg, other));
  }
  __syncthreads();

  for (int t = 0; t <= 512; ++t) {
    const uint4* hp = (const uint4*)(&h2s[0]);
    uint4 ha = hp[2 * m], hb = hp[2 * m + 1];
    h2v g0 = u2h(ha.x), g1 = u2h(ha.y), g2 = u2h(ha.z), g3 = u2h(ha.w);
    h2v g4 = u2h(hb.x), g5 = u2h(hb.y), g6 = u2h(hb.z), g7 = u2h(hb.w);
    float pc0 = reduce8s(DDOT(0, 0), DDOT(0, 1), DDOT(0, 2), DDOT(0, 3),
                         DDOT(0, 4), DDOT(0, 5), DDOT(0, 6), DDOT(0, 7));
    float pc1 = reduce8s(DDOT(1, 0), DDOT(1, 1), DDOT(1, 2), DDOT(1, 3),
                         DDOT(1, 4), DDOT(1, 5), DDOT(1, 6), DDOT(1, 7));
    aBuf[64 * w + l] = ((m < 8) ? pc0 : pc1) + bown;
    __syncthreads();
    if (tid < 256) {
      int sel = labs[t];
      const float* gsel = &gisf[sel * 768];
      float r = sigf(gsel[tid] + aBuf[tid]);
      float z = sigf(gsel[256 + tid] + aBuf[256 + tid]);
      float nn = tanhfast(gsel[512 + tid] + r * aBuf[512 + tid]);
      float hn = (1.f - z) * nn + z * hreg;
      hreg = hn;
      float other = __shfl_xor(hn, 1, 64);
      if ((tid & 1) == 0) h2s[tid >> 1] = h2u(pk2(hn, other));
      float p0 = owsh[tid] * hn, p1 = owsh[256 + tid] * hn;
      float p2 = owsh[512 + tid] * hn, p3 = owsh[768 + tid] * hn;
#pragma unroll
      for (int off = 32; off > 0; off >>= 1) {
        p0 += __shfl_xor(p0, off, 64);
        p1 += __shfl_xor(p1, off, 64);
        p2 += __shfl_xor(p2, off, 64);
        p3 += __shfl_xor(p3, off, 64);
      }
      if ((tid & 63) == 0) {
        int ww = tid >> 6;
        red[ww][0] = p0; red[ww][1] = p1; red[ww][2] = p2; red[ww][3] = p3;
      }
    }
    __syncthreads();
    if (tid == 0) {
      float l0 = red[0][0] + red[1][0] + red[2][0] + red[3][0] + b0;
      float l1 = red[0][1] + red[1][1] + red[2][1] + red[3][1] + b1;
      float l2 = red[0][2] + red[1][2] + red[2][2] + red[3][2] + b2;
      float l3 = red[0][3] + red[1][3] + red[2][3] + red[3][3] + b3;
      float mm = fmaxf(fmaxf(l0, l1), fmaxf(l2, l3));
      float s = __expf(l0 - mm) + __expf(l1 - mm) + __expf(l2 - mm) + __expf(l3 - mm);
      float lse = mm + __logf(s);
      float* o = out + ((size_t)c * 513 + t) * 4;
      o[0] = l0 - lse; o[1] = l1 - lse; o[2] = l2 - lse; o[3] = l3 - lse;
    }
  }
}

// ---------------------------------------------------------------------------
// K6: labels (as float) and weights passthrough
// ---------------------------------------------------------------------------
__global__ void k_passthrough(const int* __restrict__ labels,
                              const float* __restrict__ weights,
                              float* __restrict__ out) {
  int i = blockIdx.x * blockDim.x + threadIdx.x;
  if (i < 40960) {
    out[164160 + i] = (float)labels[i];
    out[164160 + 40960 + i] = weights[i];
  }
}

// ---------------------------------------------------------------------------
extern "C" void kernel_launch(void* const* d_in, const int* in_sizes, int n_in,
                              void* d_out, int out_size, void* d_ws, size_t ws_size,
                              hipStream_t stream) {
  (void)in_sizes; (void)n_in; (void)out_size; (void)ws_size;
  const float* feat = (const float*)d_in[0];
  const float* score = (const float*)d_in[1];
  const float* box = (const float*)d_in[2];
  const float* orig = (const float*)d_in[3];
  const int* labels = (const int*)d_in[4];
  const float* weights = (const float*)d_in[5];
  const float* appear_W = (const float*)d_in[8];
  const float* appear_b = (const float*)d_in[9];
  const float* featlin_W = (const float*)d_in[10];
  const float* featlin_b = (const float*)d_in[11];
  const float* eWihF = (const float*)d_in[12];
  const float* eWhhF = (const float*)d_in[13];
  const float* ebihF = (const float*)d_in[14];
  const float* ebhhF = (const float*)d_in[15];
  const float* eWihB = (const float*)d_in[16];
  const float* eWhhB = (const float*)d_in[17];
  const float* ebihB = (const float*)d_in[18];
  const float* ebhhB = (const float*)d_in[19];
  const float* dec_emb = (const float*)d_in[20];
  const float* dWih = (const float*)d_in[21];
  const float* dWhh = (const float*)d_in[22];
  const float* dbih = (const float*)d_in[23];
  const float* dbhh = (const float*)d_in[24];
  const float* outW = (const float*)d_in[25];
  const float* outB = (const float*)d_in[26];
  float* out = (float*)d_out;

  char* ws = (char*)d_ws;
  float* allf = (float*)ws;                                     // 40960*224 f32
  unsigned* encf2 = (unsigned*)(ws + (size_t)40960 * 224 * 4);  // 40960*64 u32
  float* dec_h0 = (float*)(ws + (size_t)40960 * 224 * 4 + (size_t)40960 * 64 * 4);
  float* dec_gi = dec_h0 + 80 * 256;                            // 80*4*768 f32

  k_fill_misc<<<15360, 256, 0, stream>>>(score, box, orig, allf);
  k_gemm_appear<<<640, 256, 0, stream>>>(feat, appear_W, appear_b, allf);
  k_gemm_featlin<<<640, 256, 0, stream>>>(allf, featlin_W, featlin_b, encf2);
  k_dec_gi<<<80, 256, 0, stream>>>(dWih, dbih, dec_emb, dec_gi);
  k_enc_gru<<<160, 512, 0, stream>>>(encf2, eWihF, eWhhF, ebihF, ebhhF,
                                     eWihB, eWhhB, ebihB, ebhhB, dec_h0);
  k_dec_gru<<<80, 768, 0, stream>>>(dWhh, dbhh, dec_gi, dec_h0, labels, outW, outB, out);
  k_passthrough<<<160, 256, 0, stream>>>(labels, weights, out);
}